// Round 12
// baseline (1163.639 us; speedup 1.0000x reference)
//
#include <hip/hip_runtime.h>
#include <math.h>

#define N_NODES 100000
#define N_EDGES 3200000
#define D_FEAT 128
#define H1 32
#define H2 16
#define NC 8

#define NBUCK 782          // buckets of 128 dst nodes: ceil(100000/128)
#define BCAP 8192          // fixed ebuf slots per bucket (mean 4096, sigma ~64)
#define EPB 8192           // edges per k_bscatter block
#define EPT 16             // edges per thread (EPB / 512)

typedef short s16x8 __attribute__((ext_vector_type(8)));
typedef float f32x4 __attribute__((ext_vector_type(4)));

// bf16 helpers (round-to-nearest-even pack, shift-expand)
__device__ inline unsigned short f2bf(float f) {
    unsigned int u = __float_as_uint(f);
    u += 0x7FFF + ((u >> 16) & 1);
    return (unsigned short)(u >> 16);
}
__device__ inline float bf2f(unsigned short h) {
    return __uint_as_float((unsigned int)h << 16);
}

// ---------------- pass A: bucket scatter via block-local LDS counting sort ---
// Inline dtype detect (first 8 KB is valid under both layouts; int64 => odd
// words zero). Output writes are linear in LDS-sorted order into
// per-(block,bucket) exclusive segments at region b*BCAP.
// ebuf entry = (src << 7) | (dst & 127): src < 2^17 -> 24 bits.

__global__ __launch_bounds__(512) void k_bscatter(const int* __restrict__ ei,
                                                  int* __restrict__ bucket_cursor,
                                                  int* __restrict__ ebuf) {
    __shared__ int hist[NBUCK];
    __shared__ int lofs[NBUCK];
    __shared__ int rank[NBUCK];
    __shared__ int gb[NBUCK];
    __shared__ int sc[512];
    __shared__ int pay[EPB];                 // 32 KB
    __shared__ unsigned short pbk[EPB];      // 16 KB
    __shared__ int det;
    const int tid = threadIdx.x;
    if (tid == 0) det = 0;
    for (int i = tid; i < NBUCK; i += 512) { hist[i] = 0; rank[i] = 0; }
    __syncthreads();
    const int odd = ei[2 * tid + 1] | ei[2 * (tid + 512) + 1];
    if (odd) atomicOr(&det, 1);
    __syncthreads();
    const bool is64 = (det == 0);
    const int e0 = blockIdx.x * EPB;
    const int n = min(EPB, N_EDGES - e0);
    int rs[EPT], rd[EPT];
#pragma unroll
    for (int k = 0; k < EPT; ++k) {
        const int i = tid + k * 512;
        if (i < n) {
            const int e = e0 + i;
            if (is64) { rs[k] = ei[2 * e]; rd[k] = ei[2 * N_EDGES + 2 * e]; }
            else      { rs[k] = ei[e];     rd[k] = ei[N_EDGES + e]; }
            atomicAdd(&hist[rd[k] >> 7], 1);
        }
    }
    __syncthreads();
    // pair-scan: thread t owns buckets 2t, 2t+1 (782 = 2*391)
    int ownp = 0;
    if (tid < 391) ownp = hist[2 * tid] + hist[2 * tid + 1];
    sc[tid] = ownp;
    __syncthreads();
    for (int off = 1; off < 512; off <<= 1) {
        const int v = (tid >= off) ? sc[tid - off] : 0;
        __syncthreads();
        sc[tid] += v;
        __syncthreads();
    }
    if (tid < 391) {
        const int base = sc[tid] - ownp;
        const int b0 = 2 * tid, b1 = 2 * tid + 1;
        lofs[b0] = base;
        lofs[b1] = base + hist[b0];
        if (hist[b0] > 0) gb[b0] = b0 * BCAP + atomicAdd(&bucket_cursor[b0], hist[b0]);
        if (hist[b1] > 0) gb[b1] = b1 * BCAP + atomicAdd(&bucket_cursor[b1], hist[b1]);
    }
    __syncthreads();
#pragma unroll
    for (int k = 0; k < EPT; ++k) {
        const int i = tid + k * 512;
        if (i < n) {
            const int b = rd[k] >> 7;
            const int p = lofs[b] + atomicAdd(&rank[b], 1);
            pay[p] = (rs[k] << 7) | (rd[k] & 127);
            pbk[p] = (unsigned short)b;
        }
    }
    __syncthreads();
    for (int p = tid; p < n; p += 512) {
        const int b = pbk[p];
        ebuf[gb[b] + (p - lofs[b])] = pay[p];
    }
}

// ---------------- dinv from bucket-local degree count (+ W1f frag prep) ------
// Block b counts its region's 128 per-node degrees in LDS. Block 0 also
// emits the mfma B-operand fragments of W1 (layout as R11 k_detect).

__global__ __launch_bounds__(256) void k_dinv(const int* __restrict__ ebuf,
                                              const int* __restrict__ bucket_cursor,
                                              const float* __restrict__ W1,
                                              float* __restrict__ dinv,
                                              unsigned short* __restrict__ W1f) {
    __shared__ int cnt[128];
    const int b = blockIdx.x, tid = threadIdx.x;
    if (tid < 128) cnt[tid] = 0;
    __syncthreads();
    const int nb = bucket_cursor[b];
    const int rb = b * BCAP;
    for (int i = tid; i < nb; i += 256)
        atomicAdd(&cnt[ebuf[rb + i] & 127], 1);
    __syncthreads();
    if (tid < 128) {
        const int v = (b << 7) + tid;
        if (v < N_NODES) dinv[v] = rsqrtf(1.0f + (float)cnt[tid]);  // +1 self-loop
    }
    if (b == 0) {
        for (int idx = tid; idx < 2 * 4 * 64 * 8; idx += 256) {
            const int j    = idx & 7;
            const int lane = (idx >> 3) & 63;
            const int kk   = (idx >> 9) & 3;
            const int nt   = idx >> 11;
            const int k = kk * 32 + ((lane >> 4) << 3) + j;
            const int nn = nt * 16 + (lane & 15);
            W1f[idx] = f2bf(W1[k * H1 + nn]);
        }
    }
}

// ---------------- layer 1 linear via MFMA: u1q = fp8( dinv * (x @ W1) ) ------

__global__ __launch_bounds__(256) void k_gemm1m(const float* __restrict__ x,
                                                const unsigned short* __restrict__ W1f,
                                                const float* __restrict__ dinv,
                                                unsigned int* __restrict__ u1q) {
    __shared__ float os[4][16][33];
    const int tid = threadIdx.x;
    const int w = tid >> 6;
    const int lane = tid & 63;
    const int row0 = (blockIdx.x * 4 + w) * 16;
    const bool act = (row0 < N_NODES);
    if (act) {
        const int m = lane & 15;
        const int quad = lane >> 4;
        const s16x8* bf = (const s16x8*)W1f;
        f32x4 acc0 = {0.f, 0.f, 0.f, 0.f};
        f32x4 acc1 = {0.f, 0.f, 0.f, 0.f};
#pragma unroll
        for (int kk = 0; kk < 4; ++kk) {
            const float* xp = x + (size_t)(row0 + m) * D_FEAT + kk * 32 + quad * 8;
            const float4 p0 = ((const float4*)xp)[0];
            const float4 p1 = ((const float4*)xp)[1];
            s16x8 a;
            a[0] = (short)f2bf(p0.x); a[1] = (short)f2bf(p0.y);
            a[2] = (short)f2bf(p0.z); a[3] = (short)f2bf(p0.w);
            a[4] = (short)f2bf(p1.x); a[5] = (short)f2bf(p1.y);
            a[6] = (short)f2bf(p1.z); a[7] = (short)f2bf(p1.w);
            acc0 = __builtin_amdgcn_mfma_f32_16x16x32_bf16(a, bf[kk * 64 + lane], acc0, 0, 0, 0);
            acc1 = __builtin_amdgcn_mfma_f32_16x16x32_bf16(a, bf[(4 + kk) * 64 + lane], acc1, 0, 0, 0);
        }
#pragma unroll
        for (int r = 0; r < 4; ++r) {
            os[w][quad * 4 + r][m]      = acc0[r];
            os[w][quad * 4 + r][16 + m] = acc1[r];
        }
    }
    __syncthreads();
    if (act) {
        const int rl = lane >> 2;       // row-in-wave 0..15
        const int seg = lane & 3;       // 8-col segment
        const int row = row0 + rl;
        const float dv = dinv[row];
        const float* p = &os[w][rl][seg * 8];
        unsigned int pk0 = __builtin_amdgcn_cvt_pk_fp8_f32(p[0] * dv, p[1] * dv, 0u, false);
        pk0 = __builtin_amdgcn_cvt_pk_fp8_f32(p[2] * dv, p[3] * dv, pk0, true);
        unsigned int pk1 = __builtin_amdgcn_cvt_pk_fp8_f32(p[4] * dv, p[5] * dv, 0u, false);
        pk1 = __builtin_amdgcn_cvt_pk_fp8_f32(p[6] * dv, p[7] * dv, pk1, true);
        uint2 o; o.x = pk0; o.y = pk1;
        ((uint2*)u1q)[(size_t)row * 4 + seg] = o;
    }
}

// ---------------- agg layer 1: LDS-tile accumulate + fused bias/relu/GEMM2 ---
// One block per bucket. hs init = self term; edges add rows via ds_add_f32
// (pad 33 => stride==1 mod 32, random dst => ~2-way bank aliasing, free).

__global__ __launch_bounds__(256) void k_agg1(const int* __restrict__ ebuf,
                                              const int* __restrict__ bucket_cursor,
                                              const float* __restrict__ dinv,
                                              const unsigned int* __restrict__ u1q,
                                              const float* __restrict__ b1,
                                              const float* __restrict__ W2,
                                              unsigned int* __restrict__ u2b) {
    __shared__ float hs[128][33];   // 16.9 KB
    __shared__ float Ws[H1 * H2];
    __shared__ float b1s[H1];
    __shared__ float dvs[128];
    const int b = blockIdx.x, tid = threadIdx.x;
    for (int i = tid; i < H1 * H2; i += 256) Ws[i] = W2[i];
    if (tid < H1) b1s[tid] = b1[tid];
    const int v0 = b << 7;
    if (tid < 128) dvs[tid] = (v0 + tid < N_NODES) ? dinv[v0 + tid] : 0.f;
    for (int i = tid; i < 128 * 8; i += 256) {   // self-loop init (decoded fp8)
        const int n = i >> 3, d = i & 7;
        const int v = v0 + n;
        const unsigned int q = (v < N_NODES) ? u1q[(size_t)v * 8 + d] : 0u;
        hs[n][d * 4 + 0] = __builtin_amdgcn_cvt_f32_fp8(q, 0);
        hs[n][d * 4 + 1] = __builtin_amdgcn_cvt_f32_fp8(q, 1);
        hs[n][d * 4 + 2] = __builtin_amdgcn_cvt_f32_fp8(q, 2);
        hs[n][d * 4 + 3] = __builtin_amdgcn_cvt_f32_fp8(q, 3);
    }
    __syncthreads();
    const int nb = bucket_cursor[b];
    const int rb = b * BCAP;
    for (int i = tid; i < nb; i += 256) {
        const int pk = ebuf[rb + i];
        const int s = pk >> 7;
        float* row = hs[pk & 127];
        const uint4 qa = ((const uint4*)u1q)[(size_t)s * 2 + 0];
        const uint4 qb = ((const uint4*)u1q)[(size_t)s * 2 + 1];
        atomicAdd(&row[0],  __builtin_amdgcn_cvt_f32_fp8(qa.x, 0));
        atomicAdd(&row[1],  __builtin_amdgcn_cvt_f32_fp8(qa.x, 1));
        atomicAdd(&row[2],  __builtin_amdgcn_cvt_f32_fp8(qa.x, 2));
        atomicAdd(&row[3],  __builtin_amdgcn_cvt_f32_fp8(qa.x, 3));
        atomicAdd(&row[4],  __builtin_amdgcn_cvt_f32_fp8(qa.y, 0));
        atomicAdd(&row[5],  __builtin_amdgcn_cvt_f32_fp8(qa.y, 1));
        atomicAdd(&row[6],  __builtin_amdgcn_cvt_f32_fp8(qa.y, 2));
        atomicAdd(&row[7],  __builtin_amdgcn_cvt_f32_fp8(qa.y, 3));
        atomicAdd(&row[8],  __builtin_amdgcn_cvt_f32_fp8(qa.z, 0));
        atomicAdd(&row[9],  __builtin_amdgcn_cvt_f32_fp8(qa.z, 1));
        atomicAdd(&row[10], __builtin_amdgcn_cvt_f32_fp8(qa.z, 2));
        atomicAdd(&row[11], __builtin_amdgcn_cvt_f32_fp8(qa.z, 3));
        atomicAdd(&row[12], __builtin_amdgcn_cvt_f32_fp8(qa.w, 0));
        atomicAdd(&row[13], __builtin_amdgcn_cvt_f32_fp8(qa.w, 1));
        atomicAdd(&row[14], __builtin_amdgcn_cvt_f32_fp8(qa.w, 2));
        atomicAdd(&row[15], __builtin_amdgcn_cvt_f32_fp8(qa.w, 3));
        atomicAdd(&row[16], __builtin_amdgcn_cvt_f32_fp8(qb.x, 0));
        atomicAdd(&row[17], __builtin_amdgcn_cvt_f32_fp8(qb.x, 1));
        atomicAdd(&row[18], __builtin_amdgcn_cvt_f32_fp8(qb.x, 2));
        atomicAdd(&row[19], __builtin_amdgcn_cvt_f32_fp8(qb.x, 3));
        atomicAdd(&row[20], __builtin_amdgcn_cvt_f32_fp8(qb.y, 0));
        atomicAdd(&row[21], __builtin_amdgcn_cvt_f32_fp8(qb.y, 1));
        atomicAdd(&row[22], __builtin_amdgcn_cvt_f32_fp8(qb.y, 2));
        atomicAdd(&row[23], __builtin_amdgcn_cvt_f32_fp8(qb.y, 3));
        atomicAdd(&row[24], __builtin_amdgcn_cvt_f32_fp8(qb.z, 0));
        atomicAdd(&row[25], __builtin_amdgcn_cvt_f32_fp8(qb.z, 1));
        atomicAdd(&row[26], __builtin_amdgcn_cvt_f32_fp8(qb.z, 2));
        atomicAdd(&row[27], __builtin_amdgcn_cvt_f32_fp8(qb.z, 3));
        atomicAdd(&row[28], __builtin_amdgcn_cvt_f32_fp8(qb.w, 0));
        atomicAdd(&row[29], __builtin_amdgcn_cvt_f32_fp8(qb.w, 1));
        atomicAdd(&row[30], __builtin_amdgcn_cvt_f32_fp8(qb.w, 2));
        atomicAdd(&row[31], __builtin_amdgcn_cvt_f32_fp8(qb.w, 3));
    }
    __syncthreads();
    // h = relu(sum * dinv + b1), in place
    for (int i = tid; i < 128 * 32; i += 256) {
        const int n = i >> 5, k = i & 31;
        hs[n][k] = fmaxf(fmaf(hs[n][k], dvs[n], b1s[k]), 0.0f);
    }
    __syncthreads();
    // GEMM2: 2 threads/node, 8 outputs each; u2b = bf16(dinv * h@W2)
    const int n = tid >> 1, half = tid & 1;
    const int v = v0 + n;
    if (v < N_NODES) {
        const int j0 = half * 8;
        float s0 = 0.f, s1 = 0.f, s2 = 0.f, s3 = 0.f;
        float s4 = 0.f, s5 = 0.f, s6 = 0.f, s7 = 0.f;
#pragma unroll
        for (int k = 0; k < H1; ++k) {
            const float hk = hs[n][k];
            s0 = fmaf(hk, Ws[k * H2 + j0 + 0], s0);
            s1 = fmaf(hk, Ws[k * H2 + j0 + 1], s1);
            s2 = fmaf(hk, Ws[k * H2 + j0 + 2], s2);
            s3 = fmaf(hk, Ws[k * H2 + j0 + 3], s3);
            s4 = fmaf(hk, Ws[k * H2 + j0 + 4], s4);
            s5 = fmaf(hk, Ws[k * H2 + j0 + 5], s5);
            s6 = fmaf(hk, Ws[k * H2 + j0 + 6], s6);
            s7 = fmaf(hk, Ws[k * H2 + j0 + 7], s7);
        }
        const float dv = dvs[n];
        uint4 o;
        o.x = (unsigned int)f2bf(s0 * dv) | ((unsigned int)f2bf(s1 * dv) << 16);
        o.y = (unsigned int)f2bf(s2 * dv) | ((unsigned int)f2bf(s3 * dv) << 16);
        o.z = (unsigned int)f2bf(s4 * dv) | ((unsigned int)f2bf(s5 * dv) << 16);
        o.w = (unsigned int)f2bf(s6 * dv) | ((unsigned int)f2bf(s7 * dv) << 16);
        ((uint4*)u2b)[(size_t)v * 2 + half] = o;
    }
}

// ---------------- agg layer 2: LDS-tile accumulate + classifier + softmax ----

__global__ __launch_bounds__(256) void k_agg2(const int* __restrict__ ebuf,
                                              const int* __restrict__ bucket_cursor,
                                              const float* __restrict__ dinv,
                                              const unsigned int* __restrict__ u2b,
                                              const float* __restrict__ b2,
                                              const float* __restrict__ Wc,
                                              const float* __restrict__ bc,
                                              float* __restrict__ out) {
    __shared__ float hs[128][17];   // 8.7 KB
    __shared__ float Wcs[H2 * NC];
    __shared__ float bcs[NC];
    __shared__ float b2s[H2];
    __shared__ float dvs[128];
    const int b = blockIdx.x, tid = threadIdx.x;
    if (tid < H2 * NC) Wcs[tid] = Wc[tid];
    if (tid < NC) bcs[tid] = bc[tid];
    if (tid < H2) b2s[tid] = b2[tid];
    const int v0 = b << 7;
    if (tid < 128) dvs[tid] = (v0 + tid < N_NODES) ? dinv[v0 + tid] : 0.f;
    for (int i = tid; i < 128 * 8; i += 256) {   // self-loop init (decoded bf16)
        const int n = i >> 3, d = i & 7;
        const int v = v0 + n;
        const unsigned int q = (v < N_NODES) ? u2b[(size_t)v * 8 + d] : 0u;
        hs[n][d * 2 + 0] = bf2f((unsigned short)q);
        hs[n][d * 2 + 1] = bf2f((unsigned short)(q >> 16));
    }
    __syncthreads();
    const int nb = bucket_cursor[b];
    const int rb = b * BCAP;
    for (int i = tid; i < nb; i += 256) {
        const int pk = ebuf[rb + i];
        const int s = pk >> 7;
        float* row = hs[pk & 127];
        const uint4 qa = ((const uint4*)u2b)[(size_t)s * 2 + 0];
        const uint4 qb = ((const uint4*)u2b)[(size_t)s * 2 + 1];
        atomicAdd(&row[0],  bf2f((unsigned short)qa.x));
        atomicAdd(&row[1],  bf2f((unsigned short)(qa.x >> 16)));
        atomicAdd(&row[2],  bf2f((unsigned short)qa.y));
        atomicAdd(&row[3],  bf2f((unsigned short)(qa.y >> 16)));
        atomicAdd(&row[4],  bf2f((unsigned short)qa.z));
        atomicAdd(&row[5],  bf2f((unsigned short)(qa.z >> 16)));
        atomicAdd(&row[6],  bf2f((unsigned short)qa.w));
        atomicAdd(&row[7],  bf2f((unsigned short)(qa.w >> 16)));
        atomicAdd(&row[8],  bf2f((unsigned short)qb.x));
        atomicAdd(&row[9],  bf2f((unsigned short)(qb.x >> 16)));
        atomicAdd(&row[10], bf2f((unsigned short)qb.y));
        atomicAdd(&row[11], bf2f((unsigned short)(qb.y >> 16)));
        atomicAdd(&row[12], bf2f((unsigned short)qb.z));
        atomicAdd(&row[13], bf2f((unsigned short)(qb.z >> 16)));
        atomicAdd(&row[14], bf2f((unsigned short)qb.w));
        atomicAdd(&row[15], bf2f((unsigned short)(qb.w >> 16)));
    }
    __syncthreads();
    // h = relu(sum * dinv + b2), in place
    for (int i = tid; i < 128 * 16; i += 256) {
        const int n = i >> 4, k = i & 15;
        hs[n][k] = fmaxf(fmaf(hs[n][k], dvs[n], b2s[k]), 0.0f);
    }
    __syncthreads();
    if (tid < 128) {
        const int v = v0 + tid;
        if (v < N_NODES) {
            float lg[NC];
#pragma unroll
            for (int j = 0; j < NC; ++j) lg[j] = bcs[j];
#pragma unroll
            for (int k = 0; k < H2; ++k) {
                const float hk = hs[tid][k];
#pragma unroll
                for (int j = 0; j < NC; ++j)
                    lg[j] = fmaf(hk, Wcs[k * NC + j], lg[j]);
            }
            float m = lg[0];
#pragma unroll
            for (int j = 1; j < NC; ++j) m = fmaxf(m, lg[j]);
            float s = 0.0f;
#pragma unroll
            for (int j = 0; j < NC; ++j) s += expf(lg[j] - m);
            const float lse = logf(s) + m;
            float4 o0, o1;
            o0.x = lg[0] - lse; o0.y = lg[1] - lse;
            o0.z = lg[2] - lse; o0.w = lg[3] - lse;
            o1.x = lg[4] - lse; o1.y = lg[5] - lse;
            o1.z = lg[6] - lse; o1.w = lg[7] - lse;
            float4* op = (float4*)(out + (size_t)v * NC);
            op[0] = o0; op[1] = o1;
        }
    }
}

// ---------------- host launch ----------------

extern "C" void kernel_launch(void* const* d_in, const int* in_sizes, int n_in,
                              void* d_out, int out_size, void* d_ws, size_t ws_size,
                              hipStream_t stream) {
    const float* x   = (const float*)d_in[0];
    const int*   ei  = (const int*)d_in[1];
    const float* W1  = (const float*)d_in[2];
    const float* b1  = (const float*)d_in[3];
    const float* W2  = (const float*)d_in[4];
    const float* b2  = (const float*)d_in[5];
    const float* Wc  = (const float*)d_in[6];
    const float* bc  = (const float*)d_in[7];
    float* out = (float*)d_out;

    // workspace layout (int units). ~33 MB total.
    int*   bucket_cursor = (int*)d_ws;                        // 1024 (782 used)
    float* dinv          = (float*)(bucket_cursor + 1024);    // 100096
    unsigned short* W1f  = (unsigned short*)(dinv + 100096);  // 4096 bf16 (2048 ints)
    unsigned int* u1q    = (unsigned int*)((int*)W1f + 2048); // 800000 dwords (fp8 table)
    unsigned int* u2b    = u1q + 800000;                      // 800000 dwords (bf16 table)
    int*   ebuf          = (int*)(u2b + 800000);              // NBUCK*BCAP = 6406144

    hipMemsetAsync(bucket_cursor, 0, NBUCK * sizeof(int), stream);
    k_bscatter<<<(N_EDGES + EPB - 1) / EPB, 512, 0, stream>>>(ei, bucket_cursor, ebuf);
    k_dinv    <<<NBUCK, 256, 0, stream>>>(ebuf, bucket_cursor, W1, dinv, W1f);
    k_gemm1m  <<<(N_NODES + 63) / 64, 256, 0, stream>>>(x, W1f, dinv, u1q);
    k_agg1    <<<NBUCK, 256, 0, stream>>>(ebuf, bucket_cursor, dinv, u1q, b1, W2, u2b);
    k_agg2    <<<NBUCK, 256, 0, stream>>>(ebuf, bucket_cursor, dinv, u2b, b2, Wc, bc, out);
}

// Round 13
// 228.154 us; speedup vs baseline: 5.1002x; 5.1002x over previous
//
#include <hip/hip_runtime.h>
#include <math.h>

#define N_NODES 100000
#define N_EDGES 3200000
#define D_FEAT 128
#define H1 32
#define H2 16
#define NC 8

#define NBUCK 782          // buckets of 128 dst nodes: ceil(100000/128)
#define BCAP 8192          // fixed ebuf slots per bucket (mean 4096, sigma ~64)
#define EPB 8192           // edges per k_bscatter block
#define EPT 16             // edges per thread (EPB / 512)

#define FSCALE 1048576.0f      // 2^20 fixed-point scale for LDS int accumulation
#define FINV   (1.0f / 1048576.0f)

typedef short s16x8 __attribute__((ext_vector_type(8)));
typedef float f32x4 __attribute__((ext_vector_type(4)));

// bf16 helpers (round-to-nearest-even pack, shift-expand)
__device__ inline unsigned short f2bf(float f) {
    unsigned int u = __float_as_uint(f);
    u += 0x7FFF + ((u >> 16) & 1);
    return (unsigned short)(u >> 16);
}
__device__ inline float bf2f(unsigned short h) {
    return __uint_as_float((unsigned int)h << 16);
}
// fixed-point encode: int(round(f * 2^20)). R12 lesson: atomicAdd(float*) on
// LDS compiles to a CAS loop (no -munsafe-fp-atomics) -> 20x slowdown; int
// LDS atomics are always native ds_add_u32.
__device__ inline int fx(float f) { return __float2int_rn(f * FSCALE); }

// ---------------- pass A: bucket scatter via block-local LDS counting sort ---
// Inline dtype detect (int64 => odd words zero). Output writes are linear in
// LDS-sorted order into per-(block,bucket) exclusive segments at b*BCAP.
// ebuf entry = (src << 7) | (dst & 127): src < 2^17 -> 24 bits.

__global__ __launch_bounds__(512) void k_bscatter(const int* __restrict__ ei,
                                                  int* __restrict__ bucket_cursor,
                                                  int* __restrict__ ebuf) {
    __shared__ int hist[NBUCK];
    __shared__ int lofs[NBUCK];
    __shared__ int rank[NBUCK];
    __shared__ int gb[NBUCK];
    __shared__ int sc[512];
    __shared__ int pay[EPB];                 // 32 KB
    __shared__ unsigned short pbk[EPB];      // 16 KB
    __shared__ int det;
    const int tid = threadIdx.x;
    if (tid == 0) det = 0;
    for (int i = tid; i < NBUCK; i += 512) { hist[i] = 0; rank[i] = 0; }
    __syncthreads();
    const int odd = ei[2 * tid + 1] | ei[2 * (tid + 512) + 1];
    if (odd) atomicOr(&det, 1);
    __syncthreads();
    const bool is64 = (det == 0);
    const int e0 = blockIdx.x * EPB;
    const int n = min(EPB, N_EDGES - e0);
    int rs[EPT], rd[EPT];
#pragma unroll
    for (int k = 0; k < EPT; ++k) {
        const int i = tid + k * 512;
        if (i < n) {
            const int e = e0 + i;
            if (is64) { rs[k] = ei[2 * e]; rd[k] = ei[2 * N_EDGES + 2 * e]; }
            else      { rs[k] = ei[e];     rd[k] = ei[N_EDGES + e]; }
            atomicAdd(&hist[rd[k] >> 7], 1);
        }
    }
    __syncthreads();
    // pair-scan: thread t owns buckets 2t, 2t+1 (782 = 2*391)
    int ownp = 0;
    if (tid < 391) ownp = hist[2 * tid] + hist[2 * tid + 1];
    sc[tid] = ownp;
    __syncthreads();
    for (int off = 1; off < 512; off <<= 1) {
        const int v = (tid >= off) ? sc[tid - off] : 0;
        __syncthreads();
        sc[tid] += v;
        __syncthreads();
    }
    if (tid < 391) {
        const int base = sc[tid] - ownp;
        const int b0 = 2 * tid, b1 = 2 * tid + 1;
        lofs[b0] = base;
        lofs[b1] = base + hist[b0];
        if (hist[b0] > 0) gb[b0] = b0 * BCAP + atomicAdd(&bucket_cursor[b0], hist[b0]);
        if (hist[b1] > 0) gb[b1] = b1 * BCAP + atomicAdd(&bucket_cursor[b1], hist[b1]);
    }
    __syncthreads();
#pragma unroll
    for (int k = 0; k < EPT; ++k) {
        const int i = tid + k * 512;
        if (i < n) {
            const int b = rd[k] >> 7;
            const int p = lofs[b] + atomicAdd(&rank[b], 1);
            pay[p] = (rs[k] << 7) | (rd[k] & 127);
            pbk[p] = (unsigned short)b;
        }
    }
    __syncthreads();
    for (int p = tid; p < n; p += 512) {
        const int b = pbk[p];
        ebuf[gb[b] + (p - lofs[b])] = pay[p];
    }
}

// ---------------- dinv from bucket-local degree count (+ W1f frag prep) ------

__global__ __launch_bounds__(256) void k_dinv(const int* __restrict__ ebuf,
                                              const int* __restrict__ bucket_cursor,
                                              const float* __restrict__ W1,
                                              float* __restrict__ dinv,
                                              unsigned short* __restrict__ W1f) {
    __shared__ int cnt[128];
    const int b = blockIdx.x, tid = threadIdx.x;
    if (tid < 128) cnt[tid] = 0;
    __syncthreads();
    const int nb = bucket_cursor[b];
    const int rb = b * BCAP;
    for (int i = tid; i < nb; i += 256)
        atomicAdd(&cnt[ebuf[rb + i] & 127], 1);
    __syncthreads();
    if (tid < 128) {
        const int v = (b << 7) + tid;
        if (v < N_NODES) dinv[v] = rsqrtf(1.0f + (float)cnt[tid]);  // +1 self-loop
    }
    if (b == 0) {
        for (int idx = tid; idx < 2 * 4 * 64 * 8; idx += 256) {
            const int j    = idx & 7;
            const int lane = (idx >> 3) & 63;
            const int kk   = (idx >> 9) & 3;
            const int nt   = idx >> 11;
            const int k = kk * 32 + ((lane >> 4) << 3) + j;
            const int nn = nt * 16 + (lane & 15);
            W1f[idx] = f2bf(W1[k * H1 + nn]);
        }
    }
}

// ---------------- layer 1 linear via MFMA: u1q = fp8( dinv * (x @ W1) ) ------

__global__ __launch_bounds__(256) void k_gemm1m(const float* __restrict__ x,
                                                const unsigned short* __restrict__ W1f,
                                                const float* __restrict__ dinv,
                                                unsigned int* __restrict__ u1q) {
    __shared__ float os[4][16][33];
    const int tid = threadIdx.x;
    const int w = tid >> 6;
    const int lane = tid & 63;
    const int row0 = (blockIdx.x * 4 + w) * 16;
    const bool act = (row0 < N_NODES);
    if (act) {
        const int m = lane & 15;
        const int quad = lane >> 4;
        const s16x8* bf = (const s16x8*)W1f;
        f32x4 acc0 = {0.f, 0.f, 0.f, 0.f};
        f32x4 acc1 = {0.f, 0.f, 0.f, 0.f};
#pragma unroll
        for (int kk = 0; kk < 4; ++kk) {
            const float* xp = x + (size_t)(row0 + m) * D_FEAT + kk * 32 + quad * 8;
            const float4 p0 = ((const float4*)xp)[0];
            const float4 p1 = ((const float4*)xp)[1];
            s16x8 a;
            a[0] = (short)f2bf(p0.x); a[1] = (short)f2bf(p0.y);
            a[2] = (short)f2bf(p0.z); a[3] = (short)f2bf(p0.w);
            a[4] = (short)f2bf(p1.x); a[5] = (short)f2bf(p1.y);
            a[6] = (short)f2bf(p1.z); a[7] = (short)f2bf(p1.w);
            acc0 = __builtin_amdgcn_mfma_f32_16x16x32_bf16(a, bf[kk * 64 + lane], acc0, 0, 0, 0);
            acc1 = __builtin_amdgcn_mfma_f32_16x16x32_bf16(a, bf[(4 + kk) * 64 + lane], acc1, 0, 0, 0);
        }
#pragma unroll
        for (int r = 0; r < 4; ++r) {
            os[w][quad * 4 + r][m]      = acc0[r];
            os[w][quad * 4 + r][16 + m] = acc1[r];
        }
    }
    __syncthreads();
    if (act) {
        const int rl = lane >> 2;       // row-in-wave 0..15
        const int seg = lane & 3;       // 8-col segment
        const int row = row0 + rl;
        const float dv = dinv[row];
        const float* p = &os[w][rl][seg * 8];
        unsigned int pk0 = __builtin_amdgcn_cvt_pk_fp8_f32(p[0] * dv, p[1] * dv, 0u, false);
        pk0 = __builtin_amdgcn_cvt_pk_fp8_f32(p[2] * dv, p[3] * dv, pk0, true);
        unsigned int pk1 = __builtin_amdgcn_cvt_pk_fp8_f32(p[4] * dv, p[5] * dv, 0u, false);
        pk1 = __builtin_amdgcn_cvt_pk_fp8_f32(p[6] * dv, p[7] * dv, pk1, true);
        uint2 o; o.x = pk0; o.y = pk1;
        ((uint2*)u1q)[(size_t)row * 4 + seg] = o;
    }
}

// ---------------- agg layer 1: fixed-point LDS accumulate + bias/relu/GEMM2 --
// One block per bucket; hsi[n][k] accumulates sum*2^20 via native ds_add_u32.

__global__ __launch_bounds__(256) void k_agg1(const int* __restrict__ ebuf,
                                              const int* __restrict__ bucket_cursor,
                                              const float* __restrict__ dinv,
                                              const unsigned int* __restrict__ u1q,
                                              const float* __restrict__ b1,
                                              const float* __restrict__ W2,
                                              unsigned int* __restrict__ u2b) {
    __shared__ int hsi[128][33];    // 16.9 KB fixed-point tile
    __shared__ float hs[128][33];   // decoded h (reused after)
    __shared__ float Ws[H1 * H2];
    __shared__ float b1s[H1];
    __shared__ float dvs[128];
    const int b = blockIdx.x, tid = threadIdx.x;
    for (int i = tid; i < H1 * H2; i += 256) Ws[i] = W2[i];
    if (tid < H1) b1s[tid] = b1[tid];
    const int v0 = b << 7;
    if (tid < 128) dvs[tid] = (v0 + tid < N_NODES) ? dinv[v0 + tid] : 0.f;
    for (int i = tid; i < 128 * 8; i += 256) {   // self-loop init (decoded fp8 -> fx)
        const int n = i >> 3, d = i & 7;
        const int v = v0 + n;
        const unsigned int q = (v < N_NODES) ? u1q[(size_t)v * 8 + d] : 0u;
        hsi[n][d * 4 + 0] = fx(__builtin_amdgcn_cvt_f32_fp8(q, 0));
        hsi[n][d * 4 + 1] = fx(__builtin_amdgcn_cvt_f32_fp8(q, 1));
        hsi[n][d * 4 + 2] = fx(__builtin_amdgcn_cvt_f32_fp8(q, 2));
        hsi[n][d * 4 + 3] = fx(__builtin_amdgcn_cvt_f32_fp8(q, 3));
    }
    __syncthreads();
    const int nb = bucket_cursor[b];
    const int rb = b * BCAP;
#pragma unroll 2
    for (int i = tid; i < nb; i += 256) {
        const int pk = ebuf[rb + i];
        const int s = pk >> 7;
        int* row = hsi[pk & 127];
        const uint4 qa = ((const uint4*)u1q)[(size_t)s * 2 + 0];
        const uint4 qb = ((const uint4*)u1q)[(size_t)s * 2 + 1];
        atomicAdd(&row[0],  fx(__builtin_amdgcn_cvt_f32_fp8(qa.x, 0)));
        atomicAdd(&row[1],  fx(__builtin_amdgcn_cvt_f32_fp8(qa.x, 1)));
        atomicAdd(&row[2],  fx(__builtin_amdgcn_cvt_f32_fp8(qa.x, 2)));
        atomicAdd(&row[3],  fx(__builtin_amdgcn_cvt_f32_fp8(qa.x, 3)));
        atomicAdd(&row[4],  fx(__builtin_amdgcn_cvt_f32_fp8(qa.y, 0)));
        atomicAdd(&row[5],  fx(__builtin_amdgcn_cvt_f32_fp8(qa.y, 1)));
        atomicAdd(&row[6],  fx(__builtin_amdgcn_cvt_f32_fp8(qa.y, 2)));
        atomicAdd(&row[7],  fx(__builtin_amdgcn_cvt_f32_fp8(qa.y, 3)));
        atomicAdd(&row[8],  fx(__builtin_amdgcn_cvt_f32_fp8(qa.z, 0)));
        atomicAdd(&row[9],  fx(__builtin_amdgcn_cvt_f32_fp8(qa.z, 1)));
        atomicAdd(&row[10], fx(__builtin_amdgcn_cvt_f32_fp8(qa.z, 2)));
        atomicAdd(&row[11], fx(__builtin_amdgcn_cvt_f32_fp8(qa.z, 3)));
        atomicAdd(&row[12], fx(__builtin_amdgcn_cvt_f32_fp8(qa.w, 0)));
        atomicAdd(&row[13], fx(__builtin_amdgcn_cvt_f32_fp8(qa.w, 1)));
        atomicAdd(&row[14], fx(__builtin_amdgcn_cvt_f32_fp8(qa.w, 2)));
        atomicAdd(&row[15], fx(__builtin_amdgcn_cvt_f32_fp8(qa.w, 3)));
        atomicAdd(&row[16], fx(__builtin_amdgcn_cvt_f32_fp8(qb.x, 0)));
        atomicAdd(&row[17], fx(__builtin_amdgcn_cvt_f32_fp8(qb.x, 1)));
        atomicAdd(&row[18], fx(__builtin_amdgcn_cvt_f32_fp8(qb.x, 2)));
        atomicAdd(&row[19], fx(__builtin_amdgcn_cvt_f32_fp8(qb.x, 3)));
        atomicAdd(&row[20], fx(__builtin_amdgcn_cvt_f32_fp8(qb.y, 0)));
        atomicAdd(&row[21], fx(__builtin_amdgcn_cvt_f32_fp8(qb.y, 1)));
        atomicAdd(&row[22], fx(__builtin_amdgcn_cvt_f32_fp8(qb.y, 2)));
        atomicAdd(&row[23], fx(__builtin_amdgcn_cvt_f32_fp8(qb.y, 3)));
        atomicAdd(&row[24], fx(__builtin_amdgcn_cvt_f32_fp8(qb.z, 0)));
        atomicAdd(&row[25], fx(__builtin_amdgcn_cvt_f32_fp8(qb.z, 1)));
        atomicAdd(&row[26], fx(__builtin_amdgcn_cvt_f32_fp8(qb.z, 2)));
        atomicAdd(&row[27], fx(__builtin_amdgcn_cvt_f32_fp8(qb.z, 3)));
        atomicAdd(&row[28], fx(__builtin_amdgcn_cvt_f32_fp8(qb.w, 0)));
        atomicAdd(&row[29], fx(__builtin_amdgcn_cvt_f32_fp8(qb.w, 1)));
        atomicAdd(&row[30], fx(__builtin_amdgcn_cvt_f32_fp8(qb.w, 2)));
        atomicAdd(&row[31], fx(__builtin_amdgcn_cvt_f32_fp8(qb.w, 3)));
    }
    __syncthreads();
    // h = relu(fx_sum * 2^-20 * dinv + b1)
    for (int i = tid; i < 128 * 32; i += 256) {
        const int n = i >> 5, k = i & 31;
        hs[n][k] = fmaxf(fmaf((float)hsi[n][k] * FINV, dvs[n], b1s[k]), 0.0f);
    }
    __syncthreads();
    // GEMM2: 2 threads/node, 8 outputs each; u2b = bf16(dinv * h@W2)
    const int n = tid >> 1, half = tid & 1;
    const int v = v0 + n;
    if (v < N_NODES) {
        const int j0 = half * 8;
        float s0 = 0.f, s1 = 0.f, s2 = 0.f, s3 = 0.f;
        float s4 = 0.f, s5 = 0.f, s6 = 0.f, s7 = 0.f;
#pragma unroll
        for (int k = 0; k < H1; ++k) {
            const float hk = hs[n][k];
            s0 = fmaf(hk, Ws[k * H2 + j0 + 0], s0);
            s1 = fmaf(hk, Ws[k * H2 + j0 + 1], s1);
            s2 = fmaf(hk, Ws[k * H2 + j0 + 2], s2);
            s3 = fmaf(hk, Ws[k * H2 + j0 + 3], s3);
            s4 = fmaf(hk, Ws[k * H2 + j0 + 4], s4);
            s5 = fmaf(hk, Ws[k * H2 + j0 + 5], s5);
            s6 = fmaf(hk, Ws[k * H2 + j0 + 6], s6);
            s7 = fmaf(hk, Ws[k * H2 + j0 + 7], s7);
        }
        const float dv = dvs[n];
        uint4 o;
        o.x = (unsigned int)f2bf(s0 * dv) | ((unsigned int)f2bf(s1 * dv) << 16);
        o.y = (unsigned int)f2bf(s2 * dv) | ((unsigned int)f2bf(s3 * dv) << 16);
        o.z = (unsigned int)f2bf(s4 * dv) | ((unsigned int)f2bf(s5 * dv) << 16);
        o.w = (unsigned int)f2bf(s6 * dv) | ((unsigned int)f2bf(s7 * dv) << 16);
        ((uint4*)u2b)[(size_t)v * 2 + half] = o;
    }
}

// ---------------- agg layer 2: fixed-point LDS accumulate + classifier -------

__global__ __launch_bounds__(256) void k_agg2(const int* __restrict__ ebuf,
                                              const int* __restrict__ bucket_cursor,
                                              const float* __restrict__ dinv,
                                              const unsigned int* __restrict__ u2b,
                                              const float* __restrict__ b2,
                                              const float* __restrict__ Wc,
                                              const float* __restrict__ bc,
                                              float* __restrict__ out) {
    __shared__ int hsi[128][17];    // 8.7 KB fixed-point tile
    __shared__ float hs[128][17];
    __shared__ float Wcs[H2 * NC];
    __shared__ float bcs[NC];
    __shared__ float b2s[H2];
    __shared__ float dvs[128];
    const int b = blockIdx.x, tid = threadIdx.x;
    if (tid < H2 * NC) Wcs[tid] = Wc[tid];
    if (tid < NC) bcs[tid] = bc[tid];
    if (tid < H2) b2s[tid] = b2[tid];
    const int v0 = b << 7;
    if (tid < 128) dvs[tid] = (v0 + tid < N_NODES) ? dinv[v0 + tid] : 0.f;
    for (int i = tid; i < 128 * 8; i += 256) {   // self-loop init
        const int n = i >> 3, d = i & 7;
        const int v = v0 + n;
        const unsigned int q = (v < N_NODES) ? u2b[(size_t)v * 8 + d] : 0u;
        hsi[n][d * 2 + 0] = fx(bf2f((unsigned short)q));
        hsi[n][d * 2 + 1] = fx(bf2f((unsigned short)(q >> 16)));
    }
    __syncthreads();
    const int nb = bucket_cursor[b];
    const int rb = b * BCAP;
#pragma unroll 2
    for (int i = tid; i < nb; i += 256) {
        const int pk = ebuf[rb + i];
        const int s = pk >> 7;
        int* row = hsi[pk & 127];
        const uint4 qa = ((const uint4*)u2b)[(size_t)s * 2 + 0];
        const uint4 qb = ((const uint4*)u2b)[(size_t)s * 2 + 1];
        atomicAdd(&row[0],  fx(bf2f((unsigned short)qa.x)));
        atomicAdd(&row[1],  fx(bf2f((unsigned short)(qa.x >> 16))));
        atomicAdd(&row[2],  fx(bf2f((unsigned short)qa.y)));
        atomicAdd(&row[3],  fx(bf2f((unsigned short)(qa.y >> 16))));
        atomicAdd(&row[4],  fx(bf2f((unsigned short)qa.z)));
        atomicAdd(&row[5],  fx(bf2f((unsigned short)(qa.z >> 16))));
        atomicAdd(&row[6],  fx(bf2f((unsigned short)qa.w)));
        atomicAdd(&row[7],  fx(bf2f((unsigned short)(qa.w >> 16))));
        atomicAdd(&row[8],  fx(bf2f((unsigned short)qb.x)));
        atomicAdd(&row[9],  fx(bf2f((unsigned short)(qb.x >> 16))));
        atomicAdd(&row[10], fx(bf2f((unsigned short)qb.y)));
        atomicAdd(&row[11], fx(bf2f((unsigned short)(qb.y >> 16))));
        atomicAdd(&row[12], fx(bf2f((unsigned short)qb.z)));
        atomicAdd(&row[13], fx(bf2f((unsigned short)(qb.z >> 16))));
        atomicAdd(&row[14], fx(bf2f((unsigned short)qb.w)));
        atomicAdd(&row[15], fx(bf2f((unsigned short)(qb.w >> 16))));
    }
    __syncthreads();
    for (int i = tid; i < 128 * 16; i += 256) {
        const int n = i >> 4, k = i & 15;
        hs[n][k] = fmaxf(fmaf((float)hsi[n][k] * FINV, dvs[n], b2s[k]), 0.0f);
    }
    __syncthreads();
    if (tid < 128) {
        const int v = v0 + tid;
        if (v < N_NODES) {
            float lg[NC];
#pragma unroll
            for (int j = 0; j < NC; ++j) lg[j] = bcs[j];
#pragma unroll
            for (int k = 0; k < H2; ++k) {
                const float hk = hs[tid][k];
#pragma unroll
                for (int j = 0; j < NC; ++j)
                    lg[j] = fmaf(hk, Wcs[k * NC + j], lg[j]);
            }
            float m = lg[0];
#pragma unroll
            for (int j = 1; j < NC; ++j) m = fmaxf(m, lg[j]);
            float s = 0.0f;
#pragma unroll
            for (int j = 0; j < NC; ++j) s += expf(lg[j] - m);
            const float lse = logf(s) + m;
            float4 o0, o1;
            o0.x = lg[0] - lse; o0.y = lg[1] - lse;
            o0.z = lg[2] - lse; o0.w = lg[3] - lse;
            o1.x = lg[4] - lse; o1.y = lg[5] - lse;
            o1.z = lg[6] - lse; o1.w = lg[7] - lse;
            float4* op = (float4*)(out + (size_t)v * NC);
            op[0] = o0; op[1] = o1;
        }
    }
}

// ---------------- host launch ----------------

extern "C" void kernel_launch(void* const* d_in, const int* in_sizes, int n_in,
                              void* d_out, int out_size, void* d_ws, size_t ws_size,
                              hipStream_t stream) {
    const float* x   = (const float*)d_in[0];
    const int*   ei  = (const int*)d_in[1];
    const float* W1  = (const float*)d_in[2];
    const float* b1  = (const float*)d_in[3];
    const float* W2  = (const float*)d_in[4];
    const float* b2  = (const float*)d_in[5];
    const float* Wc  = (const float*)d_in[6];
    const float* bc  = (const float*)d_in[7];
    float* out = (float*)d_out;

    // workspace layout (int units). ~33 MB total.
    int*   bucket_cursor = (int*)d_ws;                        // 1024 (782 used)
    float* dinv          = (float*)(bucket_cursor + 1024);    // 100096
    unsigned short* W1f  = (unsigned short*)(dinv + 100096);  // 4096 bf16 (2048 ints)
    unsigned int* u1q    = (unsigned int*)((int*)W1f + 2048); // 800000 dwords (fp8 table)
    unsigned int* u2b    = u1q + 800000;                      // 800000 dwords (bf16 table)
    int*   ebuf          = (int*)(u2b + 800000);              // NBUCK*BCAP = 6406144

    hipMemsetAsync(bucket_cursor, 0, NBUCK * sizeof(int), stream);
    k_bscatter<<<(N_EDGES + EPB - 1) / EPB, 512, 0, stream>>>(ei, bucket_cursor, ebuf);
    k_dinv    <<<NBUCK, 256, 0, stream>>>(ebuf, bucket_cursor, W1, dinv, W1f);
    k_gemm1m  <<<(N_NODES + 63) / 64, 256, 0, stream>>>(x, W1f, dinv, u1q);
    k_agg1    <<<NBUCK, 256, 0, stream>>>(ebuf, bucket_cursor, dinv, u1q, b1, W2, u2b);
    k_agg2    <<<NBUCK, 256, 0, stream>>>(ebuf, bucket_cursor, dinv, u2b, b2, Wc, bc, out);
}